// Round 2
// baseline (2997.726 us; speedup 1.0000x reference)
//
#include <hip/hip_runtime.h>

typedef _Float16 half2_t __attribute__((ext_vector_type(2)));
typedef _Float16 half8_t __attribute__((ext_vector_type(8)));

union h8pack { half8_t v; half2_t h2[4]; };

constexpr int BATCH = 512;
constexpr int SEQ   = 1000;
constexpr int HID   = 128;
constexpr int GATES = 4 * HID;   // 512
constexpr int TPB   = 512;       // one thread per gate column
constexpr int ROWS  = 2;         // batch rows per block -> 256 blocks = 1/CU

#if __has_builtin(__builtin_amdgcn_fdot2)
__device__ __forceinline__ float fdot2(half2_t a, half2_t b, float c) {
  return __builtin_amdgcn_fdot2(a, b, c, false);
}
#else
__device__ __forceinline__ float fdot2(half2_t a, half2_t b, float c) {
  return c + (float)a[0] * (float)b[0] + (float)a[1] * (float)b[1];
}
#endif

__device__ __forceinline__ float fast_sigmoid(float x) {
  x = fminf(fmaxf(x, -30.f), 30.f);
  return __fdividef(1.f, 1.f + __expf(-x));
}
__device__ __forceinline__ float fast_tanh(float x) {
  x = fminf(fmaxf(x, -15.f), 15.f);
  float e = __expf(2.f * x);
  return __fdividef(e - 1.f, e + 1.f);
}

__global__ __launch_bounds__(TPB, 2)
void lstm_persist(const float* __restrict__ y,
                  const float* __restrict__ W_ih1,
                  const float* __restrict__ W_hh1,
                  const float* __restrict__ b_ih1,
                  const float* __restrict__ b_hh1,
                  const float* __restrict__ W_ih2,
                  const float* __restrict__ W_hh2,
                  const float* __restrict__ b_ih2,
                  const float* __restrict__ b_hh2,
                  const float* __restrict__ W_lin,
                  const float* __restrict__ b_lin,
                  float* __restrict__ out)
{
  const int tid = threadIdx.x;     // 0..511 == gate index j
  const int j   = tid;
  const int r0  = blockIdx.x * ROWS;

  __shared__ alignas(16) half8_t h1_sh[ROWS][HID / 8];  // h1 state, f16
  __shared__ alignas(16) half8_t h2_sh[ROWS][HID / 8];  // h2 state, f16
  __shared__ float g1_sh[ROWS][GATES];
  __shared__ float g2_sh[ROWS][GATES];
  __shared__ float red_sh[4];

  // ---- load this thread's weight rows into registers as packed f16 ----
  half2_t w1[HID / 2], w2[HID / 2], w3[HID / 2];
  {
    const float2* p1 = (const float2*)(W_hh1 + (size_t)j * HID);
    const float2* p2 = (const float2*)(W_ih2 + (size_t)j * HID);
    const float2* p3 = (const float2*)(W_hh2 + (size_t)j * HID);
#pragma unroll
    for (int k = 0; k < HID / 2; ++k) {
      float2 a  = p1[k]; w1[k] = half2_t{(_Float16)a.x,  (_Float16)a.y};
      float2 bb = p2[k]; w2[k] = half2_t{(_Float16)bb.x, (_Float16)bb.y};
      float2 cc = p3[k]; w3[k] = half2_t{(_Float16)cc.x, (_Float16)cc.y};
    }
  }
  const float wih1  = W_ih1[j];
  const float bias1 = b_ih1[j] + b_hh1[j];
  const float bias2 = b_ih2[j] + b_hh2[j];
  const float wlin  = W_lin[tid & (HID - 1)];
  const float blin  = b_lin[0];

  // zero the h state
  if (tid < 64) {
    half8_t z = {};
    if (tid < 32) ((half8_t*)h1_sh)[tid] = z;
    else          ((half8_t*)h2_sh)[tid - 32] = z;
  }
  __syncthreads();

  const float* xr0 = y + (size_t)r0 * SEQ;
  const float* xr1 = xr0 + SEQ;
  float c1v = 0.f, c2v = 0.f;

  for (int t = 0; t < SEQ; ++t) {
    // ---------- Phase A: layer-1 raw gates (all 512 threads) ----------
    float x0 = xr0[t], x1 = xr1[t];
    float a0 = fmaf(x0, wih1, bias1);
    float a1 = fmaf(x1, wih1, bias1);
#pragma unroll
    for (int c = 0; c < HID / 8; ++c) {
      h8pack u0, u1;
      u0.v = h1_sh[0][c];
      u1.v = h1_sh[1][c];
#pragma unroll
      for (int q = 0; q < 4; ++q) {
        a0 = fdot2(w1[4 * c + q], u0.h2[q], a0);
        a1 = fdot2(w1[4 * c + q], u1.h2[q], a1);
      }
    }
    g1_sh[0][j] = a0;
    g1_sh[1][j] = a1;
    __syncthreads();

    // ---------- Phase B: layer-1 cell update (threads 0..255) ----------
    if (tid < ROWS * HID) {
      const int r = tid >> 7, jj = tid & (HID - 1);
      float gi = g1_sh[r][jj];
      float gf = g1_sh[r][jj + HID];
      float gg = g1_sh[r][jj + 2 * HID];
      float go = g1_sh[r][jj + 3 * HID];
      float iv = fast_sigmoid(gi);
      float fv = fast_sigmoid(gf);
      float gv = fast_tanh(gg);
      float ov = fast_sigmoid(go);
      c1v = fmaf(fv, c1v, iv * gv);
      float h = ov * fast_tanh(c1v);
      ((_Float16*)h1_sh)[tid] = (_Float16)h;   // [r][jj] flat == tid
    }
    __syncthreads();

    // ---------- Phase C: layer-2 raw gates (all 512 threads) ----------
    float s0a = bias2, s1a = bias2, s0b = 0.f, s1b = 0.f;
#pragma unroll
    for (int c = 0; c < HID / 8; ++c) {
      h8pack u0, u1, v0, v1;
      u0.v = h1_sh[0][c];
      u1.v = h1_sh[1][c];
      v0.v = h2_sh[0][c];
      v1.v = h2_sh[1][c];
#pragma unroll
      for (int q = 0; q < 4; ++q) {
        s0a = fdot2(w2[4 * c + q], u0.h2[q], s0a);
        s1a = fdot2(w2[4 * c + q], u1.h2[q], s1a);
        s0b = fdot2(w3[4 * c + q], v0.h2[q], s0b);
        s1b = fdot2(w3[4 * c + q], v1.h2[q], s1b);
      }
    }
    g2_sh[0][j] = s0a + s0b;
    g2_sh[1][j] = s1a + s1b;
    __syncthreads();

    // ---------- Phase D: layer-2 cell update + output (threads 0..255) ----------
    float pred = 0.f;
    if (tid < ROWS * HID) {
      const int r = tid >> 7, jj = tid & (HID - 1);
      float gi = g2_sh[r][jj];
      float gf = g2_sh[r][jj + HID];
      float gg = g2_sh[r][jj + 2 * HID];
      float go = g2_sh[r][jj + 3 * HID];
      float iv = fast_sigmoid(gi);
      float fv = fast_sigmoid(gf);
      float gv = fast_tanh(gg);
      float ov = fast_sigmoid(go);
      c2v = fmaf(fv, c2v, iv * gv);
      float h = ov * fast_tanh(c2v);
      ((_Float16*)h2_sh)[tid] = (_Float16)h;
      pred = h * wlin;                       // fp32 output dot
#pragma unroll
      for (int off = 32; off > 0; off >>= 1)
        pred += __shfl_down(pred, off);
      if ((tid & 63) == 0) red_sh[tid >> 6] = pred;
    }
    __syncthreads();
    if (tid < ROWS) {
      out[(size_t)(r0 + tid) * SEQ + t] = red_sh[2 * tid] + red_sh[2 * tid + 1] + blin;
    }
  }
}

extern "C" void kernel_launch(void* const* d_in, const int* in_sizes, int n_in,
                              void* d_out, int out_size, void* d_ws, size_t ws_size,
                              hipStream_t stream) {
  const float* y     = (const float*)d_in[0];
  const float* W_ih1 = (const float*)d_in[1];
  const float* W_hh1 = (const float*)d_in[2];
  const float* b_ih1 = (const float*)d_in[3];
  const float* b_hh1 = (const float*)d_in[4];
  const float* W_ih2 = (const float*)d_in[5];
  const float* W_hh2 = (const float*)d_in[6];
  const float* b_ih2 = (const float*)d_in[7];
  const float* b_hh2 = (const float*)d_in[8];
  const float* W_lin = (const float*)d_in[9];
  const float* b_lin = (const float*)d_in[10];
  float* out = (float*)d_out;

  lstm_persist<<<BATCH / ROWS, TPB, 0, stream>>>(
      y, W_ih1, W_hh1, b_ih1, b_hh1, W_ih2, W_hh2, b_ih2, b_hh2, W_lin, b_lin, out);
}